// Round 2
// baseline (332.096 us; speedup 1.0000x reference)
//
#include <hip/hip_runtime.h>
#include <hip/hip_bf16.h>

#define N_NODES 50000
#define N_EDGES 800000
#define N_GRAPHS 64
#define LSTR 136

typedef __attribute__((ext_vector_type(4))) short s4v;
typedef __attribute__((ext_vector_type(8))) short s8v;
typedef __attribute__((ext_vector_type(16))) float f16v;

struct HL { short hi, lo; };

__device__ inline HL bsplit(float f) {
    HL r;
    unsigned u = __float_as_uint(f);
    unsigned rh = (u + 0x7FFFu + ((u >> 16) & 1u)) >> 16;
    r.hi = (short)rh;
    float fh = __uint_as_float(rh << 16);
    float fl = f - fh;
    unsigned u2 = __float_as_uint(fl);
    unsigned rl = (u2 + 0x7FFFu + ((u2 >> 16) & 1u)) >> 16;
    r.lo = (short)rl;
    return r;
}

__device__ inline unsigned short f2bf(float f) {
    unsigned u = __float_as_uint(f);
    return (unsigned short)((u + 0x7FFFu + ((u >> 16) & 1u)) >> 16);
}

__device__ inline float bflo(unsigned u) { return __uint_as_float(u << 16); }
__device__ inline float bfhi(unsigned u) { return __uint_as_float(u & 0xFFFF0000u); }

// ---------------- CSR scan kernels ----------------

__global__ __launch_bounds__(512) void k_scan_a(const int* __restrict__ cnt,
                                                int* __restrict__ rowptr,
                                                int* __restrict__ bsum,
                                                float* __restrict__ dinv, int n) {
    __shared__ int s[512];
    int t = threadIdx.x;
    int i = blockIdx.x * 512 + t;
    int v = (i < n) ? cnt[i] : 0;
    if (i < n) dinv[i] = rsqrtf((float)(v + 1));
    int pv = (v + 7) & ~7;
    s[t] = pv;
    __syncthreads();
    for (int d = 1; d < 512; d <<= 1) {
        int x = (t >= d) ? s[t - d] : 0;
        __syncthreads();
        s[t] += x;
        __syncthreads();
    }
    if (i < n) rowptr[i] = s[t] - pv;
    if (t == 511) bsum[blockIdx.x] = s[511];
}

__global__ __launch_bounds__(512) void k_scan_c(int* __restrict__ rowptr,
                                                const int* __restrict__ bsum,
                                                int n, int nb) {
    __shared__ int sb[128];
    int t = threadIdx.x;
    if (t < 128) sb[t] = (t < nb) ? bsum[t] : 0;
    __syncthreads();
    for (int d = 1; d < 128; d <<= 1) {
        int x = 0;
        if (t < 128 && t >= d) x = sb[t - d];
        __syncthreads();
        if (t < 128) sb[t] += x;
        __syncthreads();
    }
    int add = (blockIdx.x > 0) ? sb[blockIdx.x - 1] : 0;
    int i = blockIdx.x * 512 + t;
    if (i < n) rowptr[i] += add;
    if (i == 0) rowptr[n] = sb[nb - 1];
}

// ---- prep combo. CNT must be zeroed (memsetAsync) BEFORE this kernel.
// b 0..63: qq | 64..199: wsplit | 200..480: colA pad | 481: dummy Hs rows | 482..: hist
__global__ __launch_bounds__(512) void k_prep(const float* __restrict__ qe,
                                              const float* __restrict__ fc0w,
                                              const float* __restrict__ fc0b,
                                              const float* __restrict__ fc1w,
                                              const float* __restrict__ fc1b,
                                              const float* __restrict__ W0,
                                              const float* __restrict__ W1,
                                              const float* __restrict__ W2,
                                              const float* __restrict__ fc2w,
                                              const int* __restrict__ ei,
                                              int* __restrict__ cnt,
                                              int* __restrict__ rank,
                                              short* __restrict__ WH,
                                              short* __restrict__ WL,
                                              unsigned* __restrict__ Hsd,
                                              unsigned short* __restrict__ colA,
                                              float* __restrict__ qq, int E) {
    int b = blockIdx.x, tid = threadIdx.x;
    if (b >= 482) {                       // histogram + rank (CNT pre-zeroed)
        int e = (b - 482) * 512 + tid;
        if (e < E) rank[e] = atomicAdd(&cnt[ei[E + e]], 1);
        return;
    }
    if (b == 481) {                       // dummy rows: HS and HS2 (contiguous regions)
        if (tid < 64) Hsd[(unsigned)N_NODES * 64u + tid] = 0u;
        if (tid >= 64 && tid < 128) Hsd[100001u * 64u + (unsigned)(tid - 64)] = 0u;
        return;
    }
    if (b >= 200) {                       // colA pad prefill: 1,150,016 ushorts as uint4
        int idx = (b - 200) * 512 + tid;
        if (idx < 143752) {
            uint4 p;
            p.x = p.y = p.z = p.w = 0xC350C350u;   // 50000 | 50000<<16
            ((uint4*)colA)[idx] = p;
        }
        return;
    }
    if (b >= 64) {                        // weight split: 136 blocks x 512 = 69632 exact
        int i = (b - 64) * 512 + tid;
        float val;
        int dst;
        if (i < 65536) {
            int mat = i >> 14, off = i & 16383;
            int k = off >> 7, n = off & 127;
            const float* src = (mat == 0) ? W0 : (mat == 1) ? W1 : (mat == 2) ? W2 : fc1w;
            val = src[k * 128 + n];
            dst = mat * 16384 + n * 128 + k;
        } else {
            int off = i - 65536;
            int k = off >> 5, n = off & 31;
            val = fc2w[k * 32 + n];
            dst = 65536 + n * 128 + k;
        }
        HL r = bsplit(val);
        WH[dst] = r.hi;
        WL[dst] = r.lo;
        return;
    }
    // question path, graph g = b
    __shared__ float qs[768];
    __shared__ float red[512];
    __shared__ float ql[128];
    const float* fc1bot = fc1w + 128 * 128;
    int g = b;
    for (int i = tid; i < 768; i += 512) qs[i] = qe[g * 768 + i];
    __syncthreads();
    int j = tid & 127, sl = tid >> 7;
    int kb = sl * 192;
    float a0 = 0, a1 = 0, a2 = 0, a3 = 0;
    for (int k = 0; k < 192; k += 4) {
        a0 += qs[kb + k + 0] * fc0w[(kb + k + 0) * 128 + j];
        a1 += qs[kb + k + 1] * fc0w[(kb + k + 1) * 128 + j];
        a2 += qs[kb + k + 2] * fc0w[(kb + k + 2) * 128 + j];
        a3 += qs[kb + k + 3] * fc0w[(kb + k + 3) * 128 + j];
    }
    red[tid] = (a0 + a1) + (a2 + a3);
    __syncthreads();
    if (tid < 128)
        ql[tid] = fmaxf(((red[tid] + red[tid + 128]) + (red[tid + 256] + red[tid + 384]))
                        + fc0b[tid], 0.f);
    __syncthreads();
    kb = sl * 32;
    float b0 = 0, b1 = 0;
    for (int k = 0; k < 32; k += 2) {
        b0 += ql[kb + k + 0] * fc1bot[(kb + k + 0) * 128 + j];
        b1 += ql[kb + k + 1] * fc1bot[(kb + k + 1) * 128 + j];
    }
    red[tid] = b0 + b1;
    __syncthreads();
    if (tid < 128)
        qq[g * 128 + tid] = ((red[tid] + red[tid + 128]) + (red[tid + 256] + red[tid + 384]))
                            + fc1b[tid];
}

// ---------------- merged layer-1 GEMM + CSR fill ----------------
__global__ __launch_bounds__(128) void k_fg(const float* __restrict__ A32,
                                            const short* __restrict__ WTh,
                                            const short* __restrict__ WTl,
                                            const float* __restrict__ dinv,
                                            unsigned short* __restrict__ oHs,
                                            const int* __restrict__ ei,
                                            const int* __restrict__ rowptr,
                                            const int* __restrict__ rank,
                                            unsigned short* __restrict__ colA,
                                            int nrows, int E, int GG) {
    const int tid = threadIdx.x;
    if (blockIdx.x >= GG) {                     // CSR fill part
        int e = (blockIdx.x - GG) * 128 + tid;
        if (e < E) colA[rowptr[ei[E + e]] + rank[e]] = (unsigned short)ei[e];
        return;
    }
    __shared__ short Ah[32 * LSTR];
    const int row0 = blockIdx.x * 32;

    #pragma unroll
    for (int i = 0; i < 8; ++i) {
        int u = i * 128 + tid;
        int r = u >> 5, c4 = u & 31;
        int gr = row0 + r;
        float4 v = make_float4(0.f, 0.f, 0.f, 0.f);
        if (gr < nrows) v = ((const float4*)A32)[(size_t)gr * 32 + c4];
        s4v h4 = {(short)f2bf(v.x), (short)f2bf(v.y), (short)f2bf(v.z), (short)f2bf(v.w)};
        *(s4v*)&Ah[r * LSTR + c4 * 4] = h4;
    }
    __syncthreads();

    const int wv = tid >> 6, lane = tid & 63;
    const int m = lane & 31, half = lane >> 5;
    const int c0 = wv * 64 + m;
    f16v acc0 = {0.f}, acc1 = {0.f};
    #pragma unroll
    for (int ks = 0; ks < 8; ++ks) {
        int ko = ks * 16 + half * 8;
        s8v ah  = *(const s8v*)&Ah[m * LSTR + ko];
        s8v bh0 = *(const s8v*)&WTh[(size_t)c0 * 128 + ko];
        s8v bl0 = *(const s8v*)&WTl[(size_t)c0 * 128 + ko];
        s8v bh1 = *(const s8v*)&WTh[(size_t)(c0 + 32) * 128 + ko];
        s8v bl1 = *(const s8v*)&WTl[(size_t)(c0 + 32) * 128 + ko];
        acc0 = __builtin_amdgcn_mfma_f32_32x32x16_bf16(ah, bh0, acc0, 0, 0, 0);
        acc0 = __builtin_amdgcn_mfma_f32_32x32x16_bf16(ah, bl0, acc0, 0, 0, 0);
        acc1 = __builtin_amdgcn_mfma_f32_32x32x16_bf16(ah, bh1, acc1, 0, 0, 0);
        acc1 = __builtin_amdgcn_mfma_f32_32x32x16_bf16(ah, bl1, acc1, 0, 0, 0);
    }

    #pragma unroll
    for (int reg = 0; reg < 16; ++reg) {
        int rl = (reg & 3) + 8 * (reg >> 2) + 4 * half;
        int gr = row0 + rl;
        if (gr >= nrows) continue;
        float sc = dinv[gr];
        oHs[(size_t)gr * 128 + c0]      = f2bf(acc0[reg] * sc);
        oHs[(size_t)gr * 128 + c0 + 32] = f2bf(acc1[reg] * sc);
    }
}

// ---------------- fused gather + GEMM, 256 thr (4 waves) ----------------
// Quarter-per-node gather: each 16-lane quarter owns one node's full 256B row
// (lane il holds cols 8il..8il+7). Per group-of-8 edges: one colA uint4 load gives
// 8 indices -> 8 independent row gathers in flight (32 rows in flight per wave).
// No cross-lane reduction at all. Inactive quarters clamp indices to dummy row
// 50000 (zeros) for uniform control flow. 2 rounds x 4 quarters = 8 nodes/wave.
template <int FC>
__global__ __launch_bounds__(256, 7) void k_gg(const unsigned* __restrict__ Hs,
                                               const int* __restrict__ rowptr,
                                               const unsigned short* __restrict__ colA,
                                               const float* __restrict__ dinv,
                                               const float* __restrict__ bias,
                                               const short* __restrict__ WTh,
                                               const short* __restrict__ WTl,
                                               const short* __restrict__ W2h,
                                               const short* __restrict__ W2l,
                                               const float* __restrict__ qq,
                                               const int* __restrict__ batch,
                                               const float* __restrict__ fc2b,
                                               unsigned short* __restrict__ oHs,
                                               float* __restrict__ out,
                                               int n) {
    __shared__ short SM[(FC ? 64 : 32) * LSTR];
    short* Ah = SM;
    const int tid = threadIdx.x;
    const int row0 = blockIdx.x * 32;
    const int wv = tid >> 6, l = tid & 63;
    const int m = l & 31, half = l >> 5;
    const int il = l & 15;
    const int q = l >> 4;
    const unsigned ilo = (unsigned)(il * 4);

    // rowptr for both rounds hoisted (per-lane loads, L2-hot sequential region)
    const int nodeA = row0 + wv * 8 + q;
    const int nodeB = nodeA + 4;
    const int eA0 = rowptr[min(nodeA, n)];
    const int eA1 = rowptr[min(nodeA + 1, n)];
    const int eB0 = rowptr[min(nodeB, n)];
    const int eB1 = rowptr[min(nodeB + 1, n)];

    #pragma unroll
    for (int r = 0; r < 2; ++r) {
        const int node = r ? nodeB : nodeA;
        const int e0 = r ? eB0 : eA0;
        const int e1 = r ? eB1 : eA1;
        const bool alive = node < n;
        const int rl = wv * 8 + r * 4 + q;

        // self row + first index quad in flight before the loop
        uint4 sf = *(const uint4*)(Hs + (unsigned)min(node, n) * 64u + ilo);
        uint4 cw = *(const uint4*)(colA + e0);

        float ac0 = 0, ac1 = 0, ac2 = 0, ac3 = 0;
        float ac4 = 0, ac5 = 0, ac6 = 0, ac7 = 0;
        const int ng = (e1 - e0) >> 3;
        int g = 0;
        while (__any(g < ng)) {
            const bool act = g < ng;
            const uint4 cur = cw;
            if (g + 1 < ng) cw = *(const uint4*)(colA + e0 + (g + 1) * 8);
            unsigned i0 = act ? (cur.x & 0xFFFFu) : 50000u;
            unsigned i1 = act ? (cur.x >> 16)     : 50000u;
            unsigned i2 = act ? (cur.y & 0xFFFFu) : 50000u;
            unsigned i3 = act ? (cur.y >> 16)     : 50000u;
            unsigned i4 = act ? (cur.z & 0xFFFFu) : 50000u;
            unsigned i5 = act ? (cur.z >> 16)     : 50000u;
            unsigned i6 = act ? (cur.w & 0xFFFFu) : 50000u;
            unsigned i7 = act ? (cur.w >> 16)     : 50000u;
            uint4 v0 = *(const uint4*)(Hs + i0 * 64u + ilo);
            uint4 v1 = *(const uint4*)(Hs + i1 * 64u + ilo);
            uint4 v2 = *(const uint4*)(Hs + i2 * 64u + ilo);
            uint4 v3 = *(const uint4*)(Hs + i3 * 64u + ilo);
            uint4 v4 = *(const uint4*)(Hs + i4 * 64u + ilo);
            uint4 v5 = *(const uint4*)(Hs + i5 * 64u + ilo);
            uint4 v6 = *(const uint4*)(Hs + i6 * 64u + ilo);
            uint4 v7 = *(const uint4*)(Hs + i7 * 64u + ilo);
            ac0 += ((bflo(v0.x) + bflo(v1.x)) + (bflo(v2.x) + bflo(v3.x)))
                 + ((bflo(v4.x) + bflo(v5.x)) + (bflo(v6.x) + bflo(v7.x)));
            ac1 += ((bfhi(v0.x) + bfhi(v1.x)) + (bfhi(v2.x) + bfhi(v3.x)))
                 + ((bfhi(v4.x) + bfhi(v5.x)) + (bfhi(v6.x) + bfhi(v7.x)));
            ac2 += ((bflo(v0.y) + bflo(v1.y)) + (bflo(v2.y) + bflo(v3.y)))
                 + ((bflo(v4.y) + bflo(v5.y)) + (bflo(v6.y) + bflo(v7.y)));
            ac3 += ((bfhi(v0.y) + bfhi(v1.y)) + (bfhi(v2.y) + bfhi(v3.y)))
                 + ((bfhi(v4.y) + bfhi(v5.y)) + (bfhi(v6.y) + bfhi(v7.y)));
            ac4 += ((bflo(v0.z) + bflo(v1.z)) + (bflo(v2.z) + bflo(v3.z)))
                 + ((bflo(v4.z) + bflo(v5.z)) + (bflo(v6.z) + bflo(v7.z)));
            ac5 += ((bfhi(v0.z) + bfhi(v1.z)) + (bfhi(v2.z) + bfhi(v3.z)))
                 + ((bfhi(v4.z) + bfhi(v5.z)) + (bfhi(v6.z) + bfhi(v7.z)));
            ac6 += ((bflo(v0.w) + bflo(v1.w)) + (bflo(v2.w) + bflo(v3.w)))
                 + ((bflo(v4.w) + bflo(v5.w)) + (bflo(v6.w) + bflo(v7.w)));
            ac7 += ((bfhi(v0.w) + bfhi(v1.w)) + (bfhi(v2.w) + bfhi(v3.w)))
                 + ((bfhi(v4.w) + bfhi(v5.w)) + (bfhi(v6.w) + bfhi(v7.w)));
            ++g;
        }
        // bias/dinv loaded after the loop (short live ranges, L1-hot)
        const float4 bA = ((const float4*)bias)[il * 2];
        const float4 bB = ((const float4*)bias)[il * 2 + 1];
        const float di = dinv[min(node, n - 1)];
        float o0 = fmaxf((ac0 + bflo(sf.x)) * di + bA.x, 0.f);
        float o1 = fmaxf((ac1 + bfhi(sf.x)) * di + bA.y, 0.f);
        float o2 = fmaxf((ac2 + bflo(sf.y)) * di + bA.z, 0.f);
        float o3 = fmaxf((ac3 + bfhi(sf.y)) * di + bA.w, 0.f);
        float o4 = fmaxf((ac4 + bflo(sf.z)) * di + bB.x, 0.f);
        float o5 = fmaxf((ac5 + bfhi(sf.z)) * di + bB.y, 0.f);
        float o6 = fmaxf((ac6 + bflo(sf.w)) * di + bB.z, 0.f);
        float o7 = fmaxf((ac7 + bfhi(sf.w)) * di + bB.w, 0.f);
        uint4 pk;
        pk.x = alive ? ((unsigned)f2bf(o0) | ((unsigned)f2bf(o1) << 16)) : 0u;
        pk.y = alive ? ((unsigned)f2bf(o2) | ((unsigned)f2bf(o3) << 16)) : 0u;
        pk.z = alive ? ((unsigned)f2bf(o4) | ((unsigned)f2bf(o5) << 16)) : 0u;
        pk.w = alive ? ((unsigned)f2bf(o6) | ((unsigned)f2bf(o7) << 16)) : 0u;
        *(uint4*)&Ah[rl * LSTR + il * 8] = pk;
    }
    __syncthreads();

    const int c0 = wv * 32 + m;                 // all 4 waves: one 32-col block each
    f16v acc = {0.f};
    #pragma unroll
    for (int ks = 0; ks < 8; ++ks) {
        int ko = ks * 16 + half * 8;
        s8v ah = *(const s8v*)&Ah[m * LSTR + ko];
        s8v bh = *(const s8v*)&WTh[(size_t)c0 * 128 + ko];
        s8v bl = *(const s8v*)&WTl[(size_t)c0 * 128 + ko];
        acc = __builtin_amdgcn_mfma_f32_32x32x16_bf16(ah, bh, acc, 0, 0, 0);
        acc = __builtin_amdgcn_mfma_f32_32x32x16_bf16(ah, bl, acc, 0, 0, 0);
    }

    if (FC == 0) {
        #pragma unroll
        for (int reg = 0; reg < 16; ++reg) {
            int rl = (reg & 3) + 8 * (reg >> 2) + 4 * half;
            int gr = row0 + rl;
            if (gr >= n) continue;
            oHs[(size_t)gr * 128 + c0] = f2bf(acc[reg] * dinv[gr]);
        }
    } else {
        short* Pl = SM + 32 * LSTR;
        __syncthreads();                        // all waves done reading Ah
        #pragma unroll
        for (int reg = 0; reg < 16; ++reg) {    // relu(+qq), split into Ah/Pl planes
            int rl = (reg & 3) + 8 * (reg >> 2) + 4 * half;
            int gr = row0 + rl;
            int g = (gr < n) ? batch[gr] : 0;
            float v = fmaxf(acc[reg] + qq[(size_t)g * 128 + c0], 0.f);
            HL p = bsplit(v);
            Ah[rl * LSTR + c0] = p.hi;
            Pl[rl * LSTR + c0] = p.lo;
        }
        __syncthreads();
        f16v acc2 = {0.f};                      // fc2, split-K across the 4 waves
        #pragma unroll
        for (int ks = 0; ks < 2; ++ks) {
            int ko = wv * 32 + ks * 16 + half * 8;
            s8v ah = *(const s8v*)&Ah[m * LSTR + ko];
            s8v al = *(const s8v*)&Pl[m * LSTR + ko];
            s8v bh = *(const s8v*)&W2h[(size_t)m * 128 + ko];
            s8v bl = *(const s8v*)&W2l[(size_t)m * 128 + ko];
            acc2 = __builtin_amdgcn_mfma_f32_32x32x16_bf16(ah, bh, acc2, 0, 0, 0);
            acc2 = __builtin_amdgcn_mfma_f32_32x32x16_bf16(ah, bl, acc2, 0, 0, 0);
            acc2 = __builtin_amdgcn_mfma_f32_32x32x16_bf16(al, bh, acc2, 0, 0, 0);
        }
        __syncthreads();                        // alias guard: Ah/Pl reads all retired
        float* red = (float*)SM;                // 12672 B <= 17408 B (Ah+Pl)
        if (wv > 0) {
            #pragma unroll
            for (int reg = 0; reg < 16; ++reg) {
                int rl = (reg & 3) + 8 * (reg >> 2) + 4 * half;
                red[(wv - 1) * 1056 + rl * 33 + m] = acc2[reg];
            }
        }
        __syncthreads();
        if (wv == 0) {
            #pragma unroll
            for (int reg = 0; reg < 16; ++reg) {
                int rl = (reg & 3) + 8 * (reg >> 2) + 4 * half;
                int gr = row0 + rl;
                if (gr < n)
                    out[(size_t)gr * 32 + m] = acc2[reg]
                        + (red[rl * 33 + m] + red[1056 + rl * 33 + m])
                        + red[2112 + rl * 33 + m] + fc2b[m];
            }
        }
    }
}

// ---------------- launch ----------------

extern "C" void kernel_launch(void* const* d_in, const int* in_sizes, int n_in,
                              void* d_out, int out_size, void* d_ws, size_t ws_size,
                              hipStream_t stream) {
    const float* x    = (const float*)d_in[0];
    const int*   ei   = (const int*)d_in[1];
    const int*   batch= (const int*)d_in[2];
    const float* qe   = (const float*)d_in[3];
    const float* W0   = (const float*)d_in[4];
    const float* b0   = (const float*)d_in[5];
    const float* W1   = (const float*)d_in[6];
    const float* b1   = (const float*)d_in[7];
    const float* W2   = (const float*)d_in[8];
    const float* b2   = (const float*)d_in[9];
    const float* fc0w = (const float*)d_in[10];
    const float* fc0b = (const float*)d_in[11];
    const float* fc1w = (const float*)d_in[12];
    const float* fc1b = (const float*)d_in[13];
    const float* fc2w = (const float*)d_in[14];
    const float* fc2b = (const float*)d_in[15];
    float* out = (float*)d_out;

    float* WS = (float*)d_ws;
    unsigned short* HS  = (unsigned short*)WS;                // bf16 [50001,128]
    unsigned short* HS2 = (unsigned short*)(WS + 3200064);    // bf16 [50001,128]
    float* DINV = WS + 6400128;              // [50016]
    float* QQ   = WS + 6450144;              // [8192]
    int*   CNT  = (int*)(WS + 6458336);      // [50016]
    int*   ROWPTR = (int*)(WS + 6508352);    // [50016]
    int*   RANK = (int*)(WS + 6558368);      // [800000]
    unsigned short* COL = (unsigned short*)(WS + 7358368);    // [1150016] ushort
    int*   BSUM = (int*)(WS + 7933376);      // [128]
    short* WTH  = (short*)(WS + 7933504);    // [69632]
    short* WTL  = WTH + 69632;               // [69632]

    const int N = N_NODES, E = N_EDGES;
    const int sb = (N + 511) / 512;          // 98
    const int gg = (N + 31) / 32;            // 1563
    const int histb = (E + 511) / 512;       // 1563
    const int fillb = (E + 127) / 128;       // 6250

    // ---- CNT zero, then prep (qq + wsplit + colA pad + dummy rows + hist) ----
    (void)hipMemsetAsync(CNT, 0, N * sizeof(int), stream);
    k_prep<<<482 + histb, 512, 0, stream>>>(qe, fc0w, fc0b, fc1w, fc1b,
                                            W0, W1, W2, fc2w, ei, CNT, RANK,
                                            WTH, WTL, (unsigned*)HS, COL, QQ, E);
    // ---- scan ----
    k_scan_a<<<sb, 512, 0, stream>>>(CNT, ROWPTR, BSUM, DINV, N);
    k_scan_c<<<sb, 512, 0, stream>>>(ROWPTR, BSUM, N, sb);
    // ---- layer-1 GEMM (x@W0 -> HS) + CSR fill, merged ----
    k_fg<<<gg + fillb, 128, 0, stream>>>(x, WTH, WTL, DINV, HS,
                                         ei, ROWPTR, RANK, COL, N, E, gg);
    // ---- layer 2: gather(HS,b0) + @W1 -> HS2 ----
    k_gg<0><<<gg, 256, 0, stream>>>((const unsigned*)HS, ROWPTR, COL, DINV, b0,
                                    WTH + 16384, WTL + 16384, nullptr, nullptr,
                                    nullptr, nullptr, nullptr, HS2, nullptr, N);
    // ---- layer 3: gather(HS2,b1) + @W2 -> HS ----
    k_gg<0><<<gg, 256, 0, stream>>>((const unsigned*)HS2, ROWPTR, COL, DINV, b1,
                                    WTH + 32768, WTL + 32768, nullptr, nullptr,
                                    nullptr, nullptr, nullptr, HS, nullptr, N);
    // ---- final: gather(HS,b2) + fc1(+qq,relu) + fc2 -> d_out ----
    k_gg<1><<<gg, 256, 0, stream>>>((const unsigned*)HS, ROWPTR, COL, DINV, b2,
                                    WTH + 49152, WTL + 49152, WTH + 65536, WTL + 65536,
                                    QQ, batch, fc2b, nullptr, out, N);
}